// Round 5
// baseline (203.555 us; speedup 1.0000x reference)
//
#include <hip/hip_runtime.h>
#include <hip/hip_bf16.h>

#define NN 8192
#define FIN 256
#define FOUT 128
#define KSPLIT 4
#define KCH (NN / KSPLIT)  // 2048
#define NT (KCH / 32)      // 64 k-steps per block

typedef __attribute__((ext_vector_type(8))) short short8;
typedef __attribute__((ext_vector_type(4))) float f32x4;
typedef __attribute__((ext_vector_type(4))) int i32x4;
typedef __attribute__((ext_vector_type(4))) unsigned int u32x4;
typedef unsigned short u16;
typedef unsigned int u32;

__device__ inline u16 bf16r(float v) {
  return __builtin_bit_cast(u16, __float2bfloat16(v));
}

// ---- fused: h = x@W (regs), e = leaky_relu(h@a), w = exp(e), gT = bf16(w*h)^T ----
__global__ __launch_bounds__(256) void k_prep(const float* __restrict__ x,
                                              const float* __restrict__ W,
                                              const float* __restrict__ a,
                                              float* __restrict__ wexp,
                                              u16* __restrict__ gT) {
  __shared__ float xs[32 * 256];
  __shared__ float ap[4][16];
  __shared__ float wsh[32];
  __shared__ u16 gsh[32][132];
  const int t = threadIdx.x;
  const int r0 = blockIdx.x * 32;

  const float4* xg = (const float4*)(x + (size_t)r0 * FIN);
  float4* xs4 = (float4*)xs;
#pragma unroll
  for (int p = 0; p < 8; ++p) xs4[p * 256 + t] = xg[p * 256 + t];
  __syncthreads();

  const int f = t & 127;
  const int half = t >> 7;
  float acc[16];
#pragma unroll
  for (int i = 0; i < 16; ++i) acc[i] = 0.f;

  const float4* xsr = (const float4*)(xs + half * 16 * 256);
  for (int k4 = 0; k4 < 64; ++k4) {
    float w0 = W[(k4 * 4 + 0) * FOUT + f];
    float w1 = W[(k4 * 4 + 1) * FOUT + f];
    float w2 = W[(k4 * 4 + 2) * FOUT + f];
    float w3 = W[(k4 * 4 + 3) * FOUT + f];
#pragma unroll
    for (int i = 0; i < 16; ++i) {
      float4 xv = xsr[i * 64 + k4];
      acc[i] = fmaf(xv.x, w0, acc[i]);
      acc[i] = fmaf(xv.y, w1, acc[i]);
      acc[i] = fmaf(xv.z, w2, acc[i]);
      acc[i] = fmaf(xv.w, w3, acc[i]);
    }
  }

  const float af = a[f];
  float part[16];
#pragma unroll
  for (int i = 0; i < 16; ++i) part[i] = acc[i] * af;
#pragma unroll
  for (int i = 0; i < 16; ++i) {
#pragma unroll
    for (int off = 32; off >= 1; off >>= 1) part[i] += __shfl_xor(part[i], off);
  }
  const int wvid = t >> 6;
  if ((t & 63) == 0) {
#pragma unroll
    for (int i = 0; i < 16; ++i) ap[wvid][i] = part[i];
  }
  __syncthreads();
  if (t < 32) {
    int i = t & 15, hh = t >> 4;
    float alpha = ap[hh * 2][i] + ap[hh * 2 + 1][i];
    float ee = alpha > 0.f ? alpha : 0.2f * alpha;
    float wv = __expf(fminf(ee, 80.f));  // softmax shift-invariance: no global max needed
    wsh[t] = wv;
    wexp[r0 + t] = wv;
  }
  __syncthreads();

#pragma unroll
  for (int i = 0; i < 16; ++i) {
    int row = half * 16 + i;
    gsh[row][f] = bf16r(acc[i] * wsh[row]);
  }
  __syncthreads();

  const int ff = t >> 1;
  const int jc = (t & 1) * 16;
  u16* dst = gT + (size_t)ff * NN + r0 + jc;
#pragma unroll
  for (int q = 0; q < 4; ++q) {
    ushort4 v;
    v.x = gsh[jc + q * 4 + 0][ff];
    v.y = gsh[jc + q * 4 + 1][ff];
    v.z = gsh[jc + q * 4 + 2][ff];
    v.w = gsh[jc + q * 4 + 3][ff];
    *(ushort4*)(dst + q * 4) = v;
  }
}

// ---- numer[ks] = adj[:,kchunk] @ g[kchunk], denom[ks] = adj @ w ----
// LDS-free, barrier-free: adj -> registers (nontemporal) -> bf16 A-frags;
// gT B-frags register-direct from L2. Each wave owns 16 rows x 128 f.
__global__ __launch_bounds__(256) void k_mm(const int* __restrict__ adj,
                                            const u16* __restrict__ gT,
                                            const float* __restrict__ wexp,
                                            float* __restrict__ numer,
                                            float* __restrict__ denom) {
  const int t = threadIdx.x;
  const int lane = t & 63;
  const int wv = t >> 6;  // 0..3
  const int i0 = blockIdx.x * 64 + wv * 16;
  const int ks = blockIdx.y;
  const int kbase = ks * KCH;
  const int r = lane & 15;    // A: row-in-tile; B: f-in-tile
  const int ksl = lane >> 4;  // k-slice 0..3

  const int* ap = adj + (size_t)(i0 + r) * NN + kbase + ksl * 8;
  const float* wp = wexp + kbase + ksl * 8;
  const u16* gp = gT + (size_t)r * NN + kbase + ksl * 8;

  f32x4 acc[8];
#pragma unroll
  for (int n = 0; n < 8; ++n) acc[n] = (f32x4){0.f, 0.f, 0.f, 0.f};
  float dpart = 0.f;

  i32x4 avE0, avE1, avO0, avO1;
  f32x4 wvE0, wvE1, wvO0, wvO1;
  short8 fbE[8], fbO[8];

  auto LDA = [&](int kt, i32x4& a0, i32x4& a1, f32x4& w0, f32x4& w1) {
    const i32x4* p = (const i32x4*)(ap + kt * 32);
    a0 = __builtin_nontemporal_load(p);
    a1 = __builtin_nontemporal_load(p + 1);
    const f32x4* q = (const f32x4*)(wp + kt * 32);
    w0 = q[0];
    w1 = q[1];
  };
  auto LDB = [&](int kt, short8* fb) {
#pragma unroll
    for (int n = 0; n < 8; ++n)
      fb[n] = *(const short8*)(gp + (size_t)n * 16 * NN + kt * 32);
  };
  auto STEP = [&](i32x4 a0, i32x4 a1, f32x4 w0, f32x4 w1, short8* fb) {
    // adj in {0,1}: (a + (b<<16)) * 0x3F80 packs two bf16 {0,1.0} values.
    u32 p0 = ((u32)a0[0] + ((u32)a0[1] << 16)) * 0x3F80u;
    u32 p1 = ((u32)a0[2] + ((u32)a0[3] << 16)) * 0x3F80u;
    u32 p2 = ((u32)a1[0] + ((u32)a1[1] << 16)) * 0x3F80u;
    u32 p3 = ((u32)a1[2] + ((u32)a1[3] << 16)) * 0x3F80u;
    u32x4 pv = {p0, p1, p2, p3};
    short8 fa = __builtin_bit_cast(short8, pv);
    dpart += (a0[0] ? w0[0] : 0.f) + (a0[1] ? w0[1] : 0.f) +
             (a0[2] ? w0[2] : 0.f) + (a0[3] ? w0[3] : 0.f) +
             (a1[0] ? w1[0] : 0.f) + (a1[1] ? w1[1] : 0.f) +
             (a1[2] ? w1[2] : 0.f) + (a1[3] ? w1[3] : 0.f);
#pragma unroll
    for (int n = 0; n < 8; ++n)
      acc[n] = __builtin_amdgcn_mfma_f32_16x16x32_bf16(fa, fb[n], acc[n], 0, 0, 0);
  };

  // prologue: A/w two steps ahead, B one step ahead
  LDA(0, avE0, avE1, wvE0, wvE1);
  LDA(1, avO0, avO1, wvO0, wvO1);
  LDB(0, fbE);

#pragma unroll 1
  for (int kt = 0; kt < NT; kt += 2) {
    {
      i32x4 a0 = avE0, a1 = avE1;
      f32x4 w0 = wvE0, w1 = wvE1;
      int ka = (kt + 2 < NT) ? kt + 2 : 0;  // clamped dead-load at tail
      LDA(ka, avE0, avE1, wvE0, wvE1);
      LDB(kt + 1, fbO);
      STEP(a0, a1, w0, w1, fbE);
    }
    {
      i32x4 a0 = avO0, a1 = avO1;
      f32x4 w0 = wvO0, w1 = wvO1;
      int ka = (kt + 3 < NT) ? kt + 3 : 0;
      LDA(ka, avO0, avO1, wvO0, wvO1);
      int kb = (kt + 2 < NT) ? kt + 2 : 0;
      LDB(kb, fbE);
      STEP(a0, a1, w0, w1, fbO);
    }
  }

  // denom: lane holds partial for row r over its k-slices; fold slices.
  dpart += __shfl_xor(dpart, 16);
  dpart += __shfl_xor(dpart, 32);
  if (lane < 16) denom[(size_t)ks * NN + i0 + lane] = dpart;

  float* np = numer + ((size_t)ks * NN + i0) * FOUT;
#pragma unroll
  for (int q = 0; q < 4; ++q) {
    int row = (lane >> 4) * 4 + q;
#pragma unroll
    for (int n = 0; n < 8; ++n)
      np[(size_t)row * FOUT + n * 16 + (lane & 15)] = acc[n][q];
  }
}

// ---- out = sum(numer) / sum(denom) ----
__global__ __launch_bounds__(256) void k_comb(const float* __restrict__ numer,
                                              const float* __restrict__ denom,
                                              float* __restrict__ out) {
  const int idx = blockIdx.x * 256 + threadIdx.x;
  const int row = idx >> 5;
  const int fc = (idx & 31) * 4;
  float4 s = {0.f, 0.f, 0.f, 0.f};
  float d = 0.f;
#pragma unroll
  for (int ks = 0; ks < KSPLIT; ++ks) {
    float4 nv = *(const float4*)(numer + ((size_t)ks * NN + row) * FOUT + fc);
    s.x += nv.x;
    s.y += nv.y;
    s.z += nv.z;
    s.w += nv.w;
    d += denom[(size_t)ks * NN + row];
  }
  float inv = 1.0f / d;
  float4 o;
  o.x = s.x * inv;
  o.y = s.y * inv;
  o.z = s.z * inv;
  o.w = s.w * inv;
  *(float4*)(out + (size_t)row * FOUT + fc) = o;
}

extern "C" void kernel_launch(void* const* d_in, const int* in_sizes, int n_in,
                              void* d_out, int out_size, void* d_ws, size_t ws_size,
                              hipStream_t stream) {
  const float* x = (const float*)d_in[0];
  const int* adj = (const int*)d_in[1];
  const float* W = (const float*)d_in[2];
  const float* a = (const float*)d_in[3];
  float* out = (float*)d_out;

  char* ws = (char*)d_ws;
  float* wexp = (float*)ws;                                  // 32 KB
  u16* gT = (u16*)(ws + (size_t)65536);                      // 2 MB
  float* numer = (float*)(ws + (size_t)65536 + 2097152);     // 16 MB (4 x 8192 x 128)
  float* denom = (float*)(ws + (size_t)65536 + 2097152 + 16777216);  // 128 KB

  hipLaunchKernelGGL(k_prep, dim3(NN / 32), dim3(256), 0, stream, x, W, a, wexp, gT);
  hipLaunchKernelGGL(k_mm, dim3(NN / 64, KSPLIT), dim3(256), 0, stream, adj, gT, wexp,
                     numer, denom);
  hipLaunchKernelGGL(k_comb, dim3((NN * FOUT / 4) / 256), dim3(256), 0, stream, numer,
                     denom, out);
}

// Round 6
// 134.655 us; speedup vs baseline: 1.5117x; 1.5117x over previous
//
#include <hip/hip_runtime.h>
#include <hip/hip_bf16.h>

#define NN 8192
#define FIN 256
#define FOUT 128
#define KSPLIT 4
#define KCH (NN / KSPLIT)  // 2048
#define BK 64
#define NT (KCH / BK)      // 32

typedef __attribute__((ext_vector_type(8))) short short8;
typedef __attribute__((ext_vector_type(4))) float f32x4;
typedef __attribute__((ext_vector_type(4))) int i32x4;
typedef __attribute__((ext_vector_type(4))) unsigned int u32x4;
typedef unsigned short u16;
typedef unsigned int u32;
typedef unsigned long long u64;
typedef unsigned char u8;

__device__ inline u16 bf16r(float v) {
  return __builtin_bit_cast(u16, __float2bfloat16(v));
}

// ---- fused: h = x@W (regs), e = leaky_relu(h@a), w = exp(e), gT = bf16(w*h)^T ----
__global__ __launch_bounds__(256) void k_prep(const float* __restrict__ x,
                                              const float* __restrict__ W,
                                              const float* __restrict__ a,
                                              float* __restrict__ wexp,
                                              u16* __restrict__ gT) {
  __shared__ float xs[32 * 256];
  __shared__ float ap[4][16];
  __shared__ float wsh[32];
  __shared__ u16 gsh[32][132];
  const int t = threadIdx.x;
  const int r0 = blockIdx.x * 32;

  const float4* xg = (const float4*)(x + (size_t)r0 * FIN);
  float4* xs4 = (float4*)xs;
#pragma unroll
  for (int p = 0; p < 8; ++p) xs4[p * 256 + t] = xg[p * 256 + t];
  __syncthreads();

  const int f = t & 127;
  const int half = t >> 7;
  float acc[16];
#pragma unroll
  for (int i = 0; i < 16; ++i) acc[i] = 0.f;

  const float4* xsr = (const float4*)(xs + half * 16 * 256);
  for (int k4 = 0; k4 < 64; ++k4) {
    float w0 = W[(k4 * 4 + 0) * FOUT + f];
    float w1 = W[(k4 * 4 + 1) * FOUT + f];
    float w2 = W[(k4 * 4 + 2) * FOUT + f];
    float w3 = W[(k4 * 4 + 3) * FOUT + f];
#pragma unroll
    for (int i = 0; i < 16; ++i) {
      float4 xv = xsr[i * 64 + k4];
      acc[i] = fmaf(xv.x, w0, acc[i]);
      acc[i] = fmaf(xv.y, w1, acc[i]);
      acc[i] = fmaf(xv.z, w2, acc[i]);
      acc[i] = fmaf(xv.w, w3, acc[i]);
    }
  }

  const float af = a[f];
  float part[16];
#pragma unroll
  for (int i = 0; i < 16; ++i) part[i] = acc[i] * af;
#pragma unroll
  for (int i = 0; i < 16; ++i) {
#pragma unroll
    for (int off = 32; off >= 1; off >>= 1) part[i] += __shfl_xor(part[i], off);
  }
  const int wvid = t >> 6;
  if ((t & 63) == 0) {
#pragma unroll
    for (int i = 0; i < 16; ++i) ap[wvid][i] = part[i];
  }
  __syncthreads();
  if (t < 32) {
    int i = t & 15, hh = t >> 4;
    float alpha = ap[hh * 2][i] + ap[hh * 2 + 1][i];
    float ee = alpha > 0.f ? alpha : 0.2f * alpha;
    float wv = __expf(fminf(ee, 80.f));  // softmax shift-invariance: no global max needed
    wsh[t] = wv;
    wexp[r0 + t] = wv;
  }
  __syncthreads();

#pragma unroll
  for (int i = 0; i < 16; ++i) {
    int row = half * 16 + i;
    gsh[row][f] = bf16r(acc[i] * wsh[row]);
  }
  __syncthreads();

  const int ff = t >> 1;
  const int jc = (t & 1) * 16;
  u16* dst = gT + (size_t)ff * NN + r0 + jc;
#pragma unroll
  for (int q = 0; q < 4; ++q) {
    ushort4 v;
    v.x = gsh[jc + q * 4 + 0][ff];
    v.y = gsh[jc + q * 4 + 1][ff];
    v.z = gsh[jc + q * 4 + 2][ff];
    v.w = gsh[jc + q * 4 + 3][ff];
    *(ushort4*)(dst + q * 4) = v;
  }
}

// ---- compress: adj row -> 1024-byte bitmask + exact denom[row] = sum(adj*w) ----
// One block per row. Fully unrolled: 8 int4 loads in flight per thread (MLP).
__global__ __launch_bounds__(256) void k_bits(const int* __restrict__ adj,
                                              const float* __restrict__ wexp,
                                              u8* __restrict__ bits,
                                              float* __restrict__ denom) {
  __shared__ float red[4];
  const int t = threadIdx.x;
  const int row = blockIdx.x;
  const int* ap = adj + (size_t)row * NN;

  i32x4 av[8];
  f32x4 wq[8];
#pragma unroll
  for (int it = 0; it < 4; ++it) {
    const i32x4* p = (const i32x4*)(ap + it * 2048 + t * 8);
    av[it * 2] = __builtin_nontemporal_load(p);
    av[it * 2 + 1] = __builtin_nontemporal_load(p + 1);
    const f32x4* q = (const f32x4*)(wexp + it * 2048 + t * 8);
    wq[it * 2] = q[0];
    wq[it * 2 + 1] = q[1];
  }
  float dpart = 0.f;
#pragma unroll
  for (int it = 0; it < 4; ++it) {
    u32 m = 0;
#pragma unroll
    for (int q2 = 0; q2 < 2; ++q2) {
      i32x4 a4 = av[it * 2 + q2];
      f32x4 w4 = wq[it * 2 + q2];
#pragma unroll
      for (int i = 0; i < 4; ++i) {
        m |= ((u32)a4[i]) << (q2 * 4 + i);
        dpart += a4[i] ? w4[i] : 0.f;
      }
    }
    __builtin_nontemporal_store((u8)m, bits + (size_t)row * 1024 + it * 256 + t);
  }
#pragma unroll
  for (int off = 32; off >= 1; off >>= 1) dpart += __shfl_xor(dpart, off);
  if ((t & 63) == 0) red[t >> 6] = dpart;
  __syncthreads();
  if (t == 0) denom[row] = red[0] + red[1] + red[2] + red[3];
}

// ---- numerP[ks] = bits[:,kchunk] (x) gT[kchunk] via bf16 MFMA ----
// A = bitmask (L3), B = gT (L2). B staged via global_load_lds with
// source-pre-swizzled XOR layout; A reg-staged (u64/row). 4 blocks/CU.
__global__ __launch_bounds__(256, 4) void k_mm2(const u8* __restrict__ bits,
                                                const u16* __restrict__ gT,
                                                float* __restrict__ numerP) {
  __shared__ u16 Bsh[2][128 * 64];  // 32 KB, [f][k] XOR-swizzled
  __shared__ u8 Ash[2][512];        // 64 rows x 8 bytes (64 k-bits)

  const int t = threadIdx.x;
  const int lane = t & 63;
  const int wv = t >> 6;  // 0..3 : row-group
  const int r0 = blockIdx.x * 64;
  const int ks = blockIdx.y;
  const int kbase = ks * KCH;

  f32x4 acc[8];
#pragma unroll
  for (int n = 0; n < 8; ++n) acc[n] = (f32x4){0.f, 0.f, 0.f, 0.f};

  auto STAGE = [&](int kt, int buf) {
    // B: 4 global_load_lds(16B) per wave; LDS linear, source pre-swizzled.
#pragma unroll
    for (int j2 = 0; j2 < 4; ++j2) {
      int j = wv * 4 + j2;                // 0..15, covers f rows j*8..j*8+7
      int f = j * 8 + (lane >> 3);
      const u16* src =
          gT + (size_t)f * NN + kbase + kt * 64 + ((lane & 7) ^ (f & 7)) * 8;
      u16* dst = &Bsh[buf][j * 512];      // wave-uniform base; HW adds lane*16
      __builtin_amdgcn_global_load_lds((const u32*)src, (u32*)dst, 16, 0, 0);
    }
    // A: wave 0 stages 64 rows x 8 bytes
    if (wv == 0) {
      u64 v = *(const u64*)(bits + (size_t)(r0 + lane) * 1024 + (kbase >> 3) +
                            kt * 8);
      *(u64*)&Ash[buf][lane * 8] = v;
    }
  };

  auto DECODE = [](u32 b) {
    u32 p0 = (b & 1u ? 0x3F80u : 0u) | (b & 2u ? 0x3F800000u : 0u);
    u32 p1 = (b & 4u ? 0x3F80u : 0u) | (b & 8u ? 0x3F800000u : 0u);
    u32 p2 = (b & 16u ? 0x3F80u : 0u) | (b & 32u ? 0x3F800000u : 0u);
    u32 p3 = (b & 64u ? 0x3F80u : 0u) | (b & 128u ? 0x3F800000u : 0u);
    u32x4 pv = {p0, p1, p2, p3};
    return __builtin_bit_cast(short8, pv);
  };

  const int rloc = lane & 15;
  const int ksl = lane >> 4;

  auto COMPUTE = [&](int buf) {
    // A: one u64 per row (16-lane broadcast), extract this lane's 2 bytes
    u64 arow = *(const u64*)&Ash[buf][(wv * 16 + rloc) * 8];
    u32 lo = (u32)arow, hi = (u32)(arow >> 32);
    short8 fa0 = DECODE((lo >> (ksl * 8)) & 0xFFu);
    short8 fa1 = DECODE((hi >> (ksl * 8)) & 0xFFu);
    const char* Bb = (const char*)&Bsh[buf][0];
#pragma unroll
    for (int n = 0; n < 8; ++n) {
      int f = n * 16 + rloc;
      int sw = (f & 7) << 4;
      short8 fb0 = *(const short8*)(Bb + f * 128 + ((ksl * 16) ^ sw));
      short8 fb1 = *(const short8*)(Bb + f * 128 + ((64 + ksl * 16) ^ sw));
      acc[n] = __builtin_amdgcn_mfma_f32_16x16x32_bf16(fa0, fb0, acc[n], 0, 0, 0);
      acc[n] = __builtin_amdgcn_mfma_f32_16x16x32_bf16(fa1, fb1, acc[n], 0, 0, 0);
    }
  };

  STAGE(0, 0);
  __syncthreads();
#pragma unroll 1
  for (int kt = 0; kt < NT; ++kt) {
    if (kt + 1 < NT) STAGE(kt + 1, (kt + 1) & 1);
    COMPUTE(kt & 1);
    __syncthreads();
  }

  float* np = numerP + ((size_t)ks * NN + r0 + wv * 16) * FOUT;
#pragma unroll
  for (int q = 0; q < 4; ++q) {
    int rw = (lane >> 4) * 4 + q;
#pragma unroll
    for (int n = 0; n < 8; ++n)
      np[(size_t)rw * FOUT + n * 16 + (lane & 15)] = acc[n][q];
  }
}

// ---- out = sum_ks(numerP) / denom ----
__global__ __launch_bounds__(256) void k_comb(const float* __restrict__ numerP,
                                              const float* __restrict__ denom,
                                              float* __restrict__ out) {
  const int idx = blockIdx.x * 256 + threadIdx.x;
  const int row = idx >> 5;
  const int fc = (idx & 31) * 4;
  float4 s = {0.f, 0.f, 0.f, 0.f};
#pragma unroll
  for (int ks = 0; ks < KSPLIT; ++ks) {
    float4 nv = *(const float4*)(numerP + ((size_t)ks * NN + row) * FOUT + fc);
    s.x += nv.x;
    s.y += nv.y;
    s.z += nv.z;
    s.w += nv.w;
  }
  float inv = 1.0f / denom[row];
  float4 o;
  o.x = s.x * inv;
  o.y = s.y * inv;
  o.z = s.z * inv;
  o.w = s.w * inv;
  *(float4*)(out + (size_t)row * FOUT + fc) = o;
}

extern "C" void kernel_launch(void* const* d_in, const int* in_sizes, int n_in,
                              void* d_out, int out_size, void* d_ws, size_t ws_size,
                              hipStream_t stream) {
  const float* x = (const float*)d_in[0];
  const int* adj = (const int*)d_in[1];
  const float* W = (const float*)d_in[2];
  const float* a = (const float*)d_in[3];
  float* out = (float*)d_out;

  char* ws = (char*)d_ws;
  float* wexp = (float*)ws;                                  // @0,     32 KB
  u16* gT = (u16*)(ws + (size_t)1 * 1024 * 1024);            // @1 MB,  2 MB
  u8* bits = (u8*)(ws + (size_t)4 * 1024 * 1024);            // @4 MB,  8 MB
  float* denom = (float*)(ws + (size_t)12 * 1024 * 1024);    // @12 MB, 32 KB
  float* numerP = (float*)(ws + (size_t)16 * 1024 * 1024);   // @16 MB, 16 MB

  hipLaunchKernelGGL(k_prep, dim3(NN / 32), dim3(256), 0, stream, x, W, a, wexp, gT);
  hipLaunchKernelGGL(k_bits, dim3(NN), dim3(256), 0, stream, adj, wexp, bits, denom);
  hipLaunchKernelGGL(k_mm2, dim3(NN / 64, KSPLIT), dim3(256), 0, stream, bits, gT,
                     numerP);
  hipLaunchKernelGGL(k_comb, dim3((NN * FOUT / 4) / 256), dim3(256), 0, stream,
                     numerP, denom, out);
}

// Round 8
// 108.417 us; speedup vs baseline: 1.8775x; 1.2420x over previous
//
#include <hip/hip_runtime.h>
#include <hip/hip_bf16.h>

#define NN 8192
#define FIN 256
#define FOUT 128
#define FP 144              // 128 h-cols + denom col (128) + 15 zero pad
#define KSPLIT 4
#define KCH (NN / KSPLIT)   // 2048
#define NT (KCH / 32)       // 64 k-steps of 32
#define PANEL_BYTES (FP * 256)  // 144 rows x 128k x 2B = 36864

typedef __attribute__((ext_vector_type(8))) short short8;
typedef __attribute__((ext_vector_type(4))) float f32x4;
typedef __attribute__((ext_vector_type(4))) int i32x4;
typedef __attribute__((ext_vector_type(4))) unsigned int u32x4;
typedef unsigned short u16;
typedef unsigned int u32;

__device__ inline u16 bf16r(float v) {
  return __builtin_bit_cast(u16, __float2bfloat16(v));
}

// ---- fused: h = x@W (regs), e = leaky_relu(h@a), w = exp(e),
//      gT[f][j] = bf16(w_j*h_jf) for f<128; gT[128][j] = bf16(w_j); 129..143 = 0 ----
__global__ __launch_bounds__(256) void k_prep(const float* __restrict__ x,
                                              const float* __restrict__ W,
                                              const float* __restrict__ a,
                                              u16* __restrict__ gT) {
  __shared__ float xs[32 * 256];
  __shared__ float ap[4][16];
  __shared__ float wsh[32];
  __shared__ u16 gsh[32][132];
  const int t = threadIdx.x;
  const int r0 = blockIdx.x * 32;

  const float4* xg = (const float4*)(x + (size_t)r0 * FIN);
  float4* xs4 = (float4*)xs;
#pragma unroll
  for (int p = 0; p < 8; ++p) xs4[p * 256 + t] = xg[p * 256 + t];
  __syncthreads();

  const int f = t & 127;
  const int half = t >> 7;
  float acc[16];
#pragma unroll
  for (int i = 0; i < 16; ++i) acc[i] = 0.f;

  const float4* xsr = (const float4*)(xs + half * 16 * 256);
  for (int k4 = 0; k4 < 64; ++k4) {
    float w0 = W[(k4 * 4 + 0) * FOUT + f];
    float w1 = W[(k4 * 4 + 1) * FOUT + f];
    float w2 = W[(k4 * 4 + 2) * FOUT + f];
    float w3 = W[(k4 * 4 + 3) * FOUT + f];
#pragma unroll
    for (int i = 0; i < 16; ++i) {
      float4 xv = xsr[i * 64 + k4];
      acc[i] = fmaf(xv.x, w0, acc[i]);
      acc[i] = fmaf(xv.y, w1, acc[i]);
      acc[i] = fmaf(xv.z, w2, acc[i]);
      acc[i] = fmaf(xv.w, w3, acc[i]);
    }
  }

  const float af = a[f];
  float part[16];
#pragma unroll
  for (int i = 0; i < 16; ++i) part[i] = acc[i] * af;
#pragma unroll
  for (int i = 0; i < 16; ++i) {
#pragma unroll
    for (int off = 32; off >= 1; off >>= 1) part[i] += __shfl_xor(part[i], off);
  }
  const int wvid = t >> 6;
  if ((t & 63) == 0) {
#pragma unroll
    for (int i = 0; i < 16; ++i) ap[wvid][i] = part[i];
  }
  __syncthreads();
  if (t < 32) {
    int i = t & 15, hh = t >> 4;
    float alpha = ap[hh * 2][i] + ap[hh * 2 + 1][i];
    float ee = alpha > 0.f ? alpha : 0.2f * alpha;
    float wv = __expf(fminf(ee, 80.f));  // softmax shift-invariance: no global max needed
    wsh[t] = wv;
  }
  __syncthreads();

#pragma unroll
  for (int i = 0; i < 16; ++i) {
    int row = half * 16 + i;
    gsh[row][f] = bf16r(acc[i] * wsh[row]);
  }
  // denom row (f=128) + zero pad rows (f=129..143), this block's 32-col slice
  if (t < 240) {
    int fz = 129 + (t >> 4);
    int j = (t & 15) * 2;
    *(u32*)&gT[(size_t)fz * NN + r0 + j] = 0u;
  }
  if (t < 32) gT[(size_t)128 * NN + r0 + t] = bf16r(wsh[t]);
  __syncthreads();

  const int ff = t >> 1;
  const int jc = (t & 1) * 16;
  u16* dst = gT + (size_t)ff * NN + r0 + jc;
#pragma unroll
  for (int q = 0; q < 4; ++q) {
    ushort4 v;
    v.x = gsh[jc + q * 4 + 0][ff];
    v.y = gsh[jc + q * 4 + 1][ff];
    v.z = gsh[jc + q * 4 + 2][ff];
    v.w = gsh[jc + q * 4 + 3][ff];
    *(ushort4*)(dst + q * 4) = v;
  }
}

// ---- numerP[ks] = adj[:, kchunk] (x) gT[kchunk]  (col 128 = denominator) ----
// A: register-direct fragment loads, 4-kt-deep static ring (consume-then-refill).
// B: 144x128 LDS panels, double-buffered, global_load_lds w/ pre-swizzled source.
// Sync: one s_barrier per 4 kt with counted vmcnt(8) (9 B-loads are older than
// the 8 in-flight A-loads -> vmcnt(8) drains exactly B, A stream stays alive).
__global__ __launch_bounds__(256, 2) void k_mm(const int* __restrict__ adj,
                                               const u16* __restrict__ gT,
                                               float* __restrict__ numerP) {
  extern __shared__ char smem[];
  const int t = threadIdx.x;
  const int lane = t & 63;
  const int wv = t >> 6;      // 0..3
  const int i0 = blockIdx.x * 64;
  const int ks = blockIdx.y;
  const int kbase = ks * KCH;
  const int rloc = lane & 15;
  const int ksl = lane >> 4;  // 0..3

  const int* aptr = adj + (size_t)(i0 + wv * 16 + rloc) * NN + kbase + ksl * 8;

  f32x4 acc[9];
#pragma unroll
  for (int n = 0; n < 9; ++n) acc[n] = (f32x4){0.f, 0.f, 0.f, 0.f};

  i32x4 Aa[4], Ab[4];  // statically indexed only (full q-unroll)

  auto ISSUE_B = [&](int p, int buf) {
    const char* gTb = (const char*)gT;
#pragma unroll
    for (int i = 0; i < 9; ++i) {
      int gi = wv * 9 + i;  // 0..35; each instr covers f-rows gi*4..gi*4+3
      int fr = gi * 4 + ksl;
      const char* src = gTb + (size_t)fr * (NN * 2) +
                        (size_t)(kbase + p * 128) * 2 +
                        ((rloc * 16) ^ ((fr & 7) << 4));
      char* dst = smem + buf * PANEL_BYTES + gi * 1024;  // wave-uniform; HW adds lane*16
      __builtin_amdgcn_global_load_lds((const u32*)src, (u32*)dst, 16, 0, 0);
    }
  };

  // prologue: panel 0 staged; A for kt=0..3 in flight
  ISSUE_B(0, 0);
  __builtin_amdgcn_sched_barrier(0);
#pragma unroll
  for (int q = 0; q < 4; ++q) {
    const i32x4* pp = (const i32x4*)(aptr + q * 32);
    Aa[q] = pp[0];
    Ab[q] = pp[1];
  }
  asm volatile("s_waitcnt vmcnt(8)" ::: "memory");
  __builtin_amdgcn_s_barrier();
  __builtin_amdgcn_sched_barrier(0);

#pragma unroll 1
  for (int p = 0; p < 16; ++p) {
    const int buf = p & 1;
    if (p < 15) {
      ISSUE_B(p + 1, buf ^ 1);
      __builtin_amdgcn_sched_barrier(0);
    }
#pragma unroll
    for (int q = 0; q < 4; ++q) {
      const int kt = p * 4 + q;
      // consume set q first (loaded 4 kt ago)...
      i32x4 a0 = Aa[q], a1 = Ab[q];
      // ...then refill set q for kt+4
      if (kt + 4 < NT) {
        const i32x4* pp = (const i32x4*)(aptr + (kt + 4) * 32);
        Aa[q] = pp[0];
        Ab[q] = pp[1];
      }
      u32 p0 = ((u32)a0[0] + ((u32)a0[1] << 16)) * 0x3F80u;
      u32 p1 = ((u32)a0[2] + ((u32)a0[3] << 16)) * 0x3F80u;
      u32 p2 = ((u32)a1[0] + ((u32)a1[1] << 16)) * 0x3F80u;
      u32 p3 = ((u32)a1[2] + ((u32)a1[3] << 16)) * 0x3F80u;
      u32x4 pv = {p0, p1, p2, p3};
      short8 fa = __builtin_bit_cast(short8, pv);
      const char* B = smem + buf * PANEL_BYTES;
      const int X = q * 64 + ksl * 16;
#pragma unroll
      for (int n = 0; n < 9; ++n) {
        int fr = n * 16 + rloc;
        short8 fb = *(const short8*)(B + fr * 256 + (X ^ ((fr & 7) << 4)));
        acc[n] = __builtin_amdgcn_mfma_f32_16x16x32_bf16(fa, fb, acc[n], 0, 0, 0);
      }
    }
    if (p < 15) {
      asm volatile("s_waitcnt vmcnt(8)" ::: "memory");
      __builtin_amdgcn_s_barrier();
      __builtin_amdgcn_sched_barrier(0);
    }
  }

  float* np = numerP + ((size_t)ks * NN + i0 + wv * 16) * FP;
#pragma unroll
  for (int qq = 0; qq < 4; ++qq) {
    int row = ksl * 4 + qq;
#pragma unroll
    for (int n = 0; n < 9; ++n)
      np[(size_t)row * FP + n * 16 + rloc] = acc[n][qq];
  }
}

// ---- out[row][f] = sum_ks numerP[ks][row][f] / sum_ks numerP[ks][row][128] ----
__global__ __launch_bounds__(256) void k_comb(const float* __restrict__ nP,
                                              float* __restrict__ out) {
  const int idx = blockIdx.x * 256 + threadIdx.x;
  const int row = idx >> 5;
  const int fc = (idx & 31) * 4;
  float4 s = {0.f, 0.f, 0.f, 0.f};
  float d = 0.f;
#pragma unroll
  for (int ks = 0; ks < KSPLIT; ++ks) {
    const float* base = nP + ((size_t)ks * NN + row) * FP;
    float4 nv = *(const float4*)(base + fc);
    s.x += nv.x;
    s.y += nv.y;
    s.z += nv.z;
    s.w += nv.w;
    d += base[128];
  }
  float inv = 1.0f / d;
  float4 o;
  o.x = s.x * inv;
  o.y = s.y * inv;
  o.z = s.z * inv;
  o.w = s.w * inv;
  *(float4*)(out + (size_t)row * FOUT + fc) = o;
}

extern "C" void kernel_launch(void* const* d_in, const int* in_sizes, int n_in,
                              void* d_out, int out_size, void* d_ws, size_t ws_size,
                              hipStream_t stream) {
  const float* x = (const float*)d_in[0];
  const int* adj = (const int*)d_in[1];
  const float* W = (const float*)d_in[2];
  const float* a = (const float*)d_in[3];
  float* out = (float*)d_out;

  char* ws = (char*)d_ws;
  u16* gT = (u16*)(ws + (size_t)1 * 1024 * 1024);           // 2.36 MB (144 x 8192)
  float* numerP = (float*)(ws + (size_t)8 * 1024 * 1024);   // 18.9 MB (4 x 8192 x 144)

  hipLaunchKernelGGL(k_prep, dim3(NN / 32), dim3(256), 0, stream, x, W, a, gT);
  hipLaunchKernelGGL(k_mm, dim3(NN / 64, KSPLIT), dim3(256), 2 * PANEL_BYTES, stream,
                     adj, gT, numerP);
  hipLaunchKernelGGL(k_comb, dim3((NN * 32) / 256), dim3(256), 0, stream, numerP, out);
}